// Round 12
// baseline (862.413 us; speedup 1.0000x reference)
//
#include <hip/hip_runtime.h>
#include <hip/hip_bf16.h>

typedef __hip_bfloat16 bf16;
typedef unsigned short ushortT;
typedef ushortT u16x1 __attribute__((ext_vector_type(1)));
typedef ushortT u16x2 __attribute__((ext_vector_type(2)));
typedef ushortT u16x4 __attribute__((ext_vector_type(4)));
typedef ushortT u16x8 __attribute__((ext_vector_type(8)));
typedef __bf16   bf16x8 __attribute__((ext_vector_type(8)));
typedef float    f32x4  __attribute__((ext_vector_type(4)));

#define N_NODES    50000
#define E_EDGES    400000
#define E_TOT      450000
#define NUM_GRAPHS 2048
#define SCAN_CHUNK 1024
#define N_CHUNKS   ((N_NODES + SCAN_CHUNK - 1) / SCAN_CHUNK)   // 49

// ---------- helpers ----------
__device__ __forceinline__ float fromb(ushortT u) {
    unsigned int i = ((unsigned int)u) << 16;
    return __builtin_bit_cast(float, i);
}
__device__ __forceinline__ ushortT tob(float v) {
    bf16 h = __float2bfloat16(v);
    return __builtin_bit_cast(ushortT, h);
}

template <int VEC> struct RawV;
template <> struct RawV<1> { using T = u16x1; };
template <> struct RawV<2> { using T = u16x2; };
template <> struct RawV<4> { using T = u16x4; };

__device__ __forceinline__ void cvtv(u16x1 r, float* f) { f[0] = fromb(r[0]); }
__device__ __forceinline__ void cvtv(u16x2 r, float* f) { f[0] = fromb(r.x); f[1] = fromb(r.y); }
__device__ __forceinline__ void cvtv(u16x4 r, float* f) { f[0] = fromb(r.x); f[1] = fromb(r.y);
                                                          f[2] = fromb(r.z); f[3] = fromb(r.w); }

// ---------- diagnostic ----------
__global__ void diag_kernel(float* out, float v) { if (threadIdx.x == 0) out[0] = v; }

// ---------- CSR build ----------
__global__ void hist_kernel(const int* __restrict__ ei, int* __restrict__ counts) {
    int e = blockIdx.x * 256 + threadIdx.x;
    if (e >= E_TOT) return;
    int d = (e < E_EDGES) ? ei[E_EDGES + e] : (e - E_EDGES);
    atomicAdd(&counts[d], 1);
}

__global__ __launch_bounds__(256) void scan_sums(const int* __restrict__ counts,
                                                 int* __restrict__ chunk_sums) {
    __shared__ int red[4];
    int base = blockIdx.x * SCAN_CHUNK;
    int t = threadIdx.x;
    int s = 0;
    #pragma unroll
    for (int i = 0; i < 4; i++) {
        int idx = base + t + i * 256;
        if (idx < N_NODES) s += counts[idx];
    }
    #pragma unroll
    for (int o = 32; o > 0; o >>= 1) s += __shfl_xor(s, o);
    if ((t & 63) == 0) red[t >> 6] = s;
    __syncthreads();
    if (t == 0) chunk_sums[blockIdx.x] = red[0] + red[1] + red[2] + red[3];
}

__global__ __launch_bounds__(64) void scan_chunks(const int* __restrict__ chunk_sums,
                                                  int* __restrict__ chunk_base) {
    int t = threadIdx.x;
    int v = (t < N_CHUNKS) ? chunk_sums[t] : 0;
    int orig = v;
    #pragma unroll
    for (int o = 1; o < 64; o <<= 1) {
        int u = __shfl_up(v, o);
        if (t >= o) v += u;
    }
    if (t < N_CHUNKS) chunk_base[t] = v - orig;   // exclusive
}

// writes offsets AND cursor
__global__ __launch_bounds__(256) void scan_write(const int* __restrict__ counts,
                                                  const int* __restrict__ chunk_base,
                                                  int* __restrict__ offsets,
                                                  int* __restrict__ cursor) {
    __shared__ int wsum[4];
    int chunk = blockIdx.x;
    int base = chunk * SCAN_CHUNK;
    int t = threadIdx.x;
    int lane = t & 63, w = t >> 6;

    int c[4];
    int e0 = base + t * 4;
    #pragma unroll
    for (int k = 0; k < 4; k++) {
        int idx = e0 + k;
        c[k] = (idx < N_NODES) ? counts[idx] : 0;
    }
    int local = c[0] + c[1] + c[2] + c[3];

    int v = local;
    #pragma unroll
    for (int o = 1; o < 64; o <<= 1) {
        int u = __shfl_up(v, o);
        if (lane >= o) v += u;
    }
    if (lane == 63) wsum[w] = v;
    __syncthreads();
    int wbase = 0;
    for (int i = 0; i < w; i++) wbase += wsum[i];

    int run = chunk_base[chunk] + wbase + (v - local);
    #pragma unroll
    for (int k = 0; k < 4; k++) {
        int idx = e0 + k;
        if (idx < N_NODES) { offsets[idx] = run; cursor[idx] = run; }
        run += c[k];
    }
    if (chunk == 0 && t == 0) offsets[N_NODES] = E_TOT;
}

__global__ void scatter_kernel(const int* __restrict__ ei, int* __restrict__ cursor,
                               int* __restrict__ srcs) {
    int e = blockIdx.x * 256 + threadIdx.x;
    if (e >= E_TOT) return;
    int s, d;
    if (e < E_EDGES) { s = ei[e]; d = ei[E_EDGES + e]; }
    else             { s = d = e - E_EDGES; }
    int pos = atomicAdd(&cursor[d], 1);
    srcs[pos] = s;
}

// ---------- merged GAT weight repack ----------
__global__ void repack_gat_kernel(const float* __restrict__ Wl2, const float* __restrict__ Wr2,
                                  const float* __restrict__ Wl3, const float* __restrict__ Wr3,
                                  ushortT* __restrict__ BpL2, ushortT* __restrict__ BpR2,
                                  ushortT* __restrict__ BpL3, ushortT* __restrict__ BpR3) {
    const int S2 = 64 * 384, S3 = 128 * 768;
    int idx = blockIdx.x * 256 + threadIdx.x;
    const float* W; ushortT* Bp; int N, local;
    if (idx < S2)                { W = Wl2; Bp = BpL2; N = 384; local = idx; }
    else if (idx < 2 * S2)       { W = Wr2; Bp = BpR2; N = 384; local = idx - S2; }
    else if (idx < 2 * S2 + S3)  { W = Wl3; Bp = BpL3; N = 768; local = idx - 2 * S2; }
    else if (idx < 2 * (S2 + S3)){ W = Wr3; Bp = BpR3; N = 768; local = idx - 2 * S2 - S3; }
    else return;
    int k = local / N, n = local % N;
    Bp[((size_t)(k >> 3) * N + n) * 8 + (k & 7)] = tob(W[(size_t)k * N + n]);
}

// ---------- merged decoder split-repack ----------
__global__ void repack_split3(const float* __restrict__ Wd1, const float* __restrict__ Wd2,
                              const float* __restrict__ Wd3,
                              ushortT* __restrict__ BhD1, ushortT* __restrict__ BlD1,
                              ushortT* __restrict__ BhD2, ushortT* __restrict__ BlD2,
                              ushortT* __restrict__ BhD3, ushortT* __restrict__ BlD3) {
    const int T1 = 64 * 256, T2 = 256 * 512, T3 = 512 * 1280;
    int idx = blockIdx.x * 256 + threadIdx.x;
    const float* W; ushortT *Bh, *Bl; int Npad, N, local;
    if (idx < T1)                { W = Wd1; Bh = BhD1; Bl = BlD1; Npad = 256;  N = 256;  local = idx; }
    else if (idx < T1 + T2)      { W = Wd2; Bh = BhD2; Bl = BlD2; Npad = 512;  N = 512;  local = idx - T1; }
    else if (idx < T1 + T2 + T3) { W = Wd3; Bh = BhD3; Bl = BlD3; Npad = 1280; N = 1160; local = idx - T1 - T2; }
    else return;
    int k = local / Npad, n = local % Npad;
    float v = (n < N) ? W[(size_t)k * N + n] : 0.f;
    ushortT h = tob(v);
    size_t o = ((size_t)(k >> 3) * Npad + n) * 8 + (k & 7);
    Bh[o] = h;
    Bl[o] = tob(v - fromb(h));
}

// ---------- layer-1 fused transform (K=11, N=192) ----------
__global__ __launch_bounds__(192) void l1_transform(const float* __restrict__ x,
                                                    const float* __restrict__ Wl,
                                                    const float* __restrict__ bl,
                                                    const float* __restrict__ Wr,
                                                    const float* __restrict__ br,
                                                    ushortT* __restrict__ XL,
                                                    ushortT* __restrict__ XR, int M) {
    __shared__ float xs[64][11];
    const int tid = threadIdx.x;
    const int bm  = blockIdx.x * 64;
    const int rows = (M - bm < 64) ? (M - bm) : 64;

    float wl[11], wr[11];
    #pragma unroll
    for (int k = 0; k < 11; k++) {
        wl[k] = Wl[k * 192 + tid];
        wr[k] = Wr[k * 192 + tid];
    }
    float blc = bl[tid], brc = br[tid];

    for (int i = tid; i < rows * 11; i += 192)
        xs[i / 11][i % 11] = x[(size_t)bm * 11 + i];
    __syncthreads();

    for (int r = 0; r < rows; r++) {
        float al = blc, ar = brc;
        #pragma unroll
        for (int k = 0; k < 11; k++) {
            float xv = xs[r][k];
            al += xv * wl[k];
            ar += xv * wr[k];
        }
        size_t o = (size_t)(bm + r) * 192 + tid;
        XL[o] = tob(al);
        XR[o] = tob(ar);
    }
}

// ---------- small fp32 SIMT GEMM (mu / logvar heads) ----------
template <bool RELU>
__global__ __launch_bounds__(256) void gemm_dec(const float* __restrict__ A,
                                                const float* __restrict__ B,
                                                const float* __restrict__ bias,
                                                float* __restrict__ C,
                                                int M, int N, int K,
                                                int lda, int ldb, int ldc) {
    __shared__ float As[32][33];
    __shared__ float Bs[32][65];
    int tid = threadIdx.x;
    int tm = tid >> 4, tn = tid & 15;
    int bm = blockIdx.y * 32, bn = blockIdx.x * 64;
    float acc[2][4] = {};
    for (int k0 = 0; k0 < K; k0 += 32) {
        #pragma unroll
        for (int i = 0; i < 4; i++) {
            int e = tid + i * 256;
            int r = e >> 5, k = e & 31;
            int row = bm + r, kk = k0 + k;
            float v = 0.f;
            if (row < M && kk < K) v = A[(size_t)row * lda + kk];
            As[k][r] = v;
        }
        #pragma unroll
        for (int i = 0; i < 8; i++) {
            int e = tid + i * 256;
            int k = e >> 6, n = e & 63;
            int kk = k0 + k, col = bn + n;
            float v = 0.f;
            if (kk < K && col < N) v = B[(size_t)kk * ldb + col];
            Bs[k][n] = v;
        }
        __syncthreads();
        #pragma unroll
        for (int k = 0; k < 32; k++) {
            float a0 = As[k][tm * 2 + 0], a1 = As[k][tm * 2 + 1];
            float b0 = Bs[k][tn * 4 + 0], b1 = Bs[k][tn * 4 + 1];
            float b2 = Bs[k][tn * 4 + 2], b3 = Bs[k][tn * 4 + 3];
            acc[0][0] += a0 * b0; acc[0][1] += a0 * b1; acc[0][2] += a0 * b2; acc[0][3] += a0 * b3;
            acc[1][0] += a1 * b0; acc[1][1] += a1 * b1; acc[1][2] += a1 * b2; acc[1][3] += a1 * b3;
        }
        __syncthreads();
    }
    #pragma unroll
    for (int i = 0; i < 2; i++) {
        int row = bm + tm * 2 + i;
        if (row >= M) continue;
        #pragma unroll
        for (int j = 0; j < 4; j++) {
            int col = bn + tn * 4 + j;
            if (col >= N) continue;
            float v = acc[i][j] + bias[col];
            if (RELU) v = fmaxf(v, 0.f);
            C[(size_t)row * ldc + col] = v;
        }
    }
}

// ---------- split-bf16 MFMA decoder GEMM ----------
template <bool RELU>
__global__ __launch_bounds__(256) void mfma_dec(const float* __restrict__ A,
                                                const ushortT* __restrict__ Bh,
                                                const ushortT* __restrict__ Bl,
                                                const float* __restrict__ bias,
                                                float* __restrict__ C,
                                                int M, int N, int K, int Npad,
                                                int lda, int ldc) {
    __shared__ ushortT Ah[4 * 128 * 8];
    __shared__ ushortT Al[4 * 128 * 8];
    const int tid = threadIdx.x;
    const int bm = blockIdx.y * 128;
    const int bn = blockIdx.x * 128;
    const int lane = tid & 63;
    const int l15 = lane & 15, lg = lane >> 4;
    const int wid = tid >> 6;
    const int wm = wid >> 1, wn = wid & 1;

    f32x4 acc[4][4] = {};

    for (int k0 = 0; k0 < K; k0 += 32) {
        __syncthreads();
        #pragma unroll
        for (int it = 0; it < 2; it++) {
            int c = tid + it * 256;
            int row = c >> 2, kg = c & 3;
            const float* ap = A + (size_t)(bm + row) * lda + k0 + kg * 8;
            u16x8 hv, lv;
            #pragma unroll
            for (int i = 0; i < 8; i++) {
                float v = ap[i];
                ushortT h = tob(v);
                hv[i] = h;
                lv[i] = tob(v - fromb(h));
            }
            int unit = (kg * 128 + row) ^ kg;
            *reinterpret_cast<u16x8*>(&Ah[unit * 8]) = hv;
            *reinterpret_cast<u16x8*>(&Al[unit * 8]) = lv;
        }
        __syncthreads();

        bf16x8 ah[4], al[4], bhf[4], blf[4];
        #pragma unroll
        for (int mf = 0; mf < 4; mf++) {
            int row = wm * 64 + mf * 16 + l15;
            int unit = (lg * 128 + row) ^ lg;
            ah[mf] = __builtin_bit_cast(bf16x8, *reinterpret_cast<const u16x8*>(&Ah[unit * 8]));
            al[mf] = __builtin_bit_cast(bf16x8, *reinterpret_cast<const u16x8*>(&Al[unit * 8]));
        }
        int kgG = (k0 >> 3) + lg;
        #pragma unroll
        for (int nf = 0; nf < 4; nf++) {
            int n = bn + wn * 64 + nf * 16 + l15;
            size_t o = ((size_t)kgG * Npad + n) * 8;
            bhf[nf] = __builtin_bit_cast(bf16x8, *reinterpret_cast<const u16x8*>(Bh + o));
            blf[nf] = __builtin_bit_cast(bf16x8, *reinterpret_cast<const u16x8*>(Bl + o));
        }
        #pragma unroll
        for (int mf = 0; mf < 4; mf++) {
            #pragma unroll
            for (int nf = 0; nf < 4; nf++) {
                acc[mf][nf] = __builtin_amdgcn_mfma_f32_16x16x32_bf16(ah[mf], bhf[nf], acc[mf][nf], 0, 0, 0);
                acc[mf][nf] = __builtin_amdgcn_mfma_f32_16x16x32_bf16(ah[mf], blf[nf], acc[mf][nf], 0, 0, 0);
                acc[mf][nf] = __builtin_amdgcn_mfma_f32_16x16x32_bf16(al[mf], bhf[nf], acc[mf][nf], 0, 0, 0);
            }
        }
    }

    #pragma unroll
    for (int nf = 0; nf < 4; nf++) {
        int col = bn + wn * 64 + nf * 16 + l15;
        if (col >= N) continue;
        float bv = bias[col];
        #pragma unroll
        for (int mf = 0; mf < 4; mf++) {
            #pragma unroll
            for (int q = 0; q < 4; q++) {
                int row = bm + wm * 64 + mf * 16 + lg * 4 + q;
                if (row < M) {
                    float v = acc[mf][nf][q] + bv;
                    if (RELU) v = fmaxf(v, 0.f);
                    C[(size_t)row * ldc + col] = v;
                }
            }
        }
    }
}

// ---------- full-width MFMA bf16 GEMM ----------
template <int K, int NW>
__global__ __launch_bounds__(256) void mfma_gemmF(const ushortT* __restrict__ A,
                                                  const ushortT* __restrict__ BpL,
                                                  const ushortT* __restrict__ BpR,
                                                  const float* __restrict__ bl,
                                                  const float* __restrict__ br,
                                                  bf16* __restrict__ XL,
                                                  bf16* __restrict__ XR,
                                                  int M) {
    constexpr int KU = K / 8;
    __shared__ ushortT Alds[KU * 128 * 8];
    const int tid = threadIdx.x;
    const int bm  = blockIdx.y * 128;
    const int bnb = blockIdx.x * 128;

    for (int u = tid; u < 128 * KU; u += 256) {
        int row = u / KU, kg = u % KU;
        int rg = bm + row; if (rg > M - 1) rg = M - 1;
        u16x8 v = *reinterpret_cast<const u16x8*>(A + (size_t)rg * K + kg * 8);
        int unit = (kg * 128 + row) ^ (kg & 7);
        *reinterpret_cast<u16x8*>(&Alds[unit * 8]) = v;
    }
    __syncthreads();

    const int lane = tid & 63;
    const int l15 = lane & 15, lg = lane >> 4;
    const int wid = tid >> 6;
    const int wm = wid >> 1, wn = wid & 1;

    f32x4 acc[4][4] = {};
    #pragma unroll
    for (int s = 0; s < K / 32; s++) {
        int kg = s * 4 + lg;
        bf16x8 a[4], b[4];
        #pragma unroll
        for (int mf = 0; mf < 4; mf++) {
            int row = wm * 64 + mf * 16 + l15;
            int unit = (kg * 128 + row) ^ (kg & 7);
            a[mf] = __builtin_bit_cast(bf16x8,
                    *reinterpret_cast<const u16x8*>(&Alds[unit * 8]));
        }
        #pragma unroll
        for (int nf = 0; nf < 4; nf++) {
            int cb = bnb + wn * 64 + nf * 16;
            const ushortT* bp; int n;
            if (cb < NW) { bp = BpL; n = cb + l15; }
            else         { bp = BpR; n = cb - NW + l15; }
            b[nf] = __builtin_bit_cast(bf16x8,
                    *reinterpret_cast<const u16x8*>(bp + ((size_t)kg * NW + n) * 8));
        }
        #pragma unroll
        for (int mf = 0; mf < 4; mf++)
            #pragma unroll
            for (int nf = 0; nf < 4; nf++)
                acc[mf][nf] = __builtin_amdgcn_mfma_f32_16x16x32_bf16(
                    a[mf], b[nf], acc[mf][nf], 0, 0, 0);
    }

    #pragma unroll
    for (int nf = 0; nf < 4; nf++) {
        int cb = bnb + wn * 64 + nf * 16;
        bf16* Cp; const float* bs; int c;
        if (cb < NW) { Cp = XL; bs = bl; c = cb + l15; }
        else         { Cp = XR; bs = br; c = cb - NW + l15; }
        float bv = bs[c];
        #pragma unroll
        for (int mf = 0; mf < 4; mf++) {
            #pragma unroll
            for (int q = 0; q < 4; q++) {
                int r = bm + wm * 64 + mf * 16 + lg * 4 + q;
                if (r < M) Cp[(size_t)r * NW + c] = __float2bfloat16(acc[mf][nf][q] + bv);
            }
        }
    }
}

// ---------- fused 3-head GAT aggregation: persistent waves, rotation-free pipeline ----
// XL/XR full-width [N, 3*CHH]; att [3*CHH] head-major; OUT [N, CHH] = relu(mean+bias).
template <int CHH>
__global__ __launch_bounds__(256) void gat_fused(const ushortT* __restrict__ XL,
                                                 const ushortT* __restrict__ XR,
                                                 const float* __restrict__ att,
                                                 const float* __restrict__ bias,
                                                 const int* __restrict__ offsets,
                                                 const int* __restrict__ srcs,
                                                 ushortT* __restrict__ OUT, int N) {
    constexpr int VEC = CHH / 64;
    constexpr int LDX = 3 * CHH;
    using RT = typename RawV<VEC>::T;
    const int lane = threadIdx.x & 63;
    const int wave = blockIdx.x * 4 + (threadIdx.x >> 6);
    const int WTOT = gridDim.x * 4;
    const int loff = VEC * lane;

    // per-wave invariants: scaled attention + bias (loaded once)
    float a06[3][VEC], a04[3][VEC], bi[VEC];
    #pragma unroll
    for (int h = 0; h < 3; h++) {
        #pragma unroll
        for (int i = 0; i < VEC; i++) {
            float a = att[h * CHH + loff + i];
            a06[h][i] = 0.6f * a;
            a04[h][i] = 0.4f * a;
        }
    }
    #pragma unroll
    for (int i = 0; i < VEC; i++) bi[i] = bias[loff + i];

    for (int n = wave; n < N; n += WTOT) {
        float xr_[3][VEC], acc[3][VEC];
        const ushortT* xrp = XR + (size_t)n * LDX + loff;
        #pragma unroll
        for (int h = 0; h < 3; h++) {
            RT xrv = *reinterpret_cast<const RT*>(xrp + h * CHH);
            #pragma unroll
            for (int i = 0; i < VEC; i++) { xr_[h][i] = fromb(xrv[i]); acc[h][i] = 0.f; }
        }
        float d0 = 0.f, d1 = 0.f, d2 = 0.f;

        const int e0 = offsets[n];
        const int deg = offsets[n + 1] - e0;

        auto process = [&](RT c0, RT c1, RT c2) {
            float xl0[VEC], xl1[VEC], xl2[VEC];
            cvtv(c0, xl0); cvtv(c1, xl1); cvtv(c2, xl2);
            float p0 = 0.f, p1 = 0.f, p2 = 0.f;
            #pragma unroll
            for (int i = 0; i < VEC; i++) {
                float v0 = xl0[i] + xr_[0][i];
                float v1 = xl1[i] + xr_[1][i];
                float v2 = xl2[i] + xr_[2][i];
                p0 = fmaf(a06[0][i], v0, p0); p0 = fmaf(a04[0][i], fabsf(v0), p0);
                p1 = fmaf(a06[1][i], v1, p1); p1 = fmaf(a04[1][i], fabsf(v1), p1);
                p2 = fmaf(a06[2][i], v2, p2); p2 = fmaf(a04[2][i], fabsf(v2), p2);
            }
            #pragma unroll
            for (int ofs = 32; ofs > 0; ofs >>= 1) {
                p0 += __shfl_xor(p0, ofs);
                p1 += __shfl_xor(p1, ofs);
                p2 += __shfl_xor(p2, ofs);
            }
            float w0 = __expf(p0), w1 = __expf(p1), w2 = __expf(p2);
            d0 += w0; d1 += w1; d2 += w2;
            #pragma unroll
            for (int i = 0; i < VEC; i++) {
                acc[0][i] = fmaf(w0, xl0[i], acc[0][i]);
                acc[1][i] = fmaf(w1, xl1[i], acc[1][i]);
                acc[2][i] = fmaf(w2, xl2[i], acc[2][i]);
            }
        };

        for (int base = 0; base < deg; base += 64) {
            int cnt = deg - base; if (cnt > 64) cnt = 64;
            int sl = srcs[e0 + base + ((lane < cnt) ? lane : (cnt - 1))];

            RT A0, A1, A2, B0, B1, B2;
            {
                const ushortT* r = XL + (size_t)__shfl(sl, 0) * LDX + loff;
                A0 = *reinterpret_cast<const RT*>(r);
                A1 = *reinterpret_cast<const RT*>(r + CHH);
                A2 = *reinterpret_cast<const RT*>(r + 2 * CHH);
            }
            // rotation-free 2-stage pipeline: all guards wave-uniform
            for (int j = 0; j < cnt; j += 2) {
                if (j + 1 < cnt) {
                    const ushortT* r = XL + (size_t)__shfl(sl, j + 1) * LDX + loff;
                    B0 = *reinterpret_cast<const RT*>(r);
                    B1 = *reinterpret_cast<const RT*>(r + CHH);
                    B2 = *reinterpret_cast<const RT*>(r + 2 * CHH);
                }
                process(A0, A1, A2);
                if (j + 1 < cnt) {
                    if (j + 2 < cnt) {
                        const ushortT* r = XL + (size_t)__shfl(sl, j + 2) * LDX + loff;
                        A0 = *reinterpret_cast<const RT*>(r);
                        A1 = *reinterpret_cast<const RT*>(r + CHH);
                        A2 = *reinterpret_cast<const RT*>(r + 2 * CHH);
                    }
                    process(B0, B1, B2);
                }
            }
        }

        float i0 = 1.f / (3.f * d0 + 1e-16f);
        float i1 = 1.f / (3.f * d1 + 1e-16f);
        float i2 = 1.f / (3.f * d2 + 1e-16f);
        RT ov;
        #pragma unroll
        for (int i = 0; i < VEC; i++) {
            float v = acc[0][i] * i0 + acc[1][i] * i1 + acc[2][i] * i2 + bi[i];
            ov[i] = tob(fmaxf(v, 0.f));
        }
        *reinterpret_cast<RT*>(&OUT[(size_t)n * CHH + loff]) = ov;
    }
}

// ---------- pool ----------
__global__ void pool_kernel(const ushortT* __restrict__ h3, const int* __restrict__ batch,
                            float* __restrict__ G) {
    int g = blockIdx.x;
    int c = threadIdx.x;
    int lo = 0, hi = N_NODES;
    while (lo < hi) { int mid = (lo + hi) >> 1; if (batch[mid] < g) lo = mid + 1; else hi = mid; }
    int s0 = lo;
    hi = N_NODES;
    while (lo < hi) { int mid = (lo + hi) >> 1; if (batch[mid] < g + 1) lo = mid + 1; else hi = mid; }
    int s1 = lo;
    float sum = 0.f;
    for (int n = s0; n < s1; n++) sum += fromb(h3[(size_t)n * 256 + c]);
    G[(size_t)g * 256 + c] = sum;
}

// ---------- output assembly ----------
__global__ void assemble_kernel(const float* __restrict__ o3, float* __restrict__ out) {
    int g = blockIdx.x;
    const float* row = o3 + (size_t)g * 1160;
    float* xrec = out + (size_t)g * 319;
    for (int p = threadIdx.x; p < 319; p += 256) xrec[p] = row[p];
    float* adj = out + 653312 + (size_t)g * 841;
    for (int p = threadIdx.x; p < 841; p += 256) {
        int i = p / 29, j = p % 29;
        adj[p] = 0.5f * (row[319 + p] + row[319 + j * 29 + i]);
    }
}

// ---------- launch ----------
extern "C" void kernel_launch(void* const* d_in, const int* in_sizes, int n_in,
                              void* d_out, int out_size, void* d_ws, size_t ws_size,
                              hipStream_t stream) {
    const float* x     = (const float*)d_in[0];
    const int*   ei    = (const int*)d_in[1];
    const int*   batch = (const int*)d_in[2];
    const float* Wl1 = (const float*)d_in[3];
    const float* bl1 = (const float*)d_in[4];
    const float* Wr1 = (const float*)d_in[5];
    const float* br1 = (const float*)d_in[6];
    const float* att1= (const float*)d_in[7];
    const float* b1  = (const float*)d_in[8];
    const float* Wl2 = (const float*)d_in[9];
    const float* bl2 = (const float*)d_in[10];
    const float* Wr2 = (const float*)d_in[11];
    const float* br2 = (const float*)d_in[12];
    const float* att2= (const float*)d_in[13];
    const float* b2  = (const float*)d_in[14];
    const float* Wl3 = (const float*)d_in[15];
    const float* bl3 = (const float*)d_in[16];
    const float* Wr3 = (const float*)d_in[17];
    const float* br3 = (const float*)d_in[18];
    const float* att3= (const float*)d_in[19];
    const float* b3  = (const float*)d_in[20];
    const float* Wmu = (const float*)d_in[21];
    const float* bmu = (const float*)d_in[22];
    const float* Wlv = (const float*)d_in[23];
    const float* blv = (const float*)d_in[24];
    const float* Wd1 = (const float*)d_in[25];
    const float* bd1 = (const float*)d_in[26];
    const float* Wd2 = (const float*)d_in[27];
    const float* bd2 = (const float*)d_in[28];
    const float* Wd3 = (const float*)d_in[29];
    const float* bd3 = (const float*)d_in[30];
    float* out = (float*)d_out;

    const int MU_OFF = 2375680;
    const int LV_OFF = 2506752;
    char* wsb = (char*)d_ws;

    const size_t NEED_FULL = 194892064;
    const dim3 AGG_GRID(2048);   // persistent: 8192 waves grid-stride over nodes

    if (ws_size < NEED_FULL) {
        hipLaunchKernelGGL(diag_kernel, dim3(1), dim3(64), 0, stream, out, (float)(ws_size >> 20));
        return;
    }

    // ---- workspace layout ----
    ushortT* h3u = (ushortT*)(wsb + 0);          // 50000x256
    ushortT* h1u = (ushortT*)(wsb + 0);          // 50000x64 (disjoint lifetime)
    ushortT* h2u = (ushortT*)(wsb + 25600000);   // 50000x128
    bf16*    XLb = (bf16*)(wsb + 38400000);      // up to 50000x768
    ushortT* XLu = (ushortT*)(wsb + 38400000);
    bf16*    XRb = (bf16*)(wsb + 115200000);
    ushortT* XRu = (ushortT*)(wsb + 115200000);
    float* G  = (float*)(wsb + 38400000);        // decoder scratch aliases XL
    float* O1 = G  + 524288;
    float* O2 = O1 + 524288;
    float* O3 = O2 + 1048576;
    ushortT* BhD3 = (ushortT*)(wsb + 115200000); // alias XR (dead after last gat)
    ushortT* BlD3 = (ushortT*)(wsb + 116600000);
    ushortT* BhD2 = (ushortT*)(wsb + 118000000);
    ushortT* BlD2 = (ushortT*)(wsb + 118300000);
    ushortT* BhD1 = (ushortT*)(wsb + 118600000);
    ushortT* BlD1 = (ushortT*)(wsb + 118700000);
    int* counts  = (int*)(wsb + 192000000);
    int* offsets = counts + (N_NODES + 1);
    int* cursor  = offsets + (N_NODES + 1);
    int* srcs    = cursor + (N_NODES + 1);
    int* chunk_sums = srcs + E_TOT;
    int* chunk_base = chunk_sums + 64;
    ushortT* BpL2 = (ushortT*)(wsb + 194400544);
    ushortT* BpR2 = (ushortT*)(wsb + 194449696);
    ushortT* BpL3 = (ushortT*)(wsb + 194498848);
    ushortT* BpR3 = (ushortT*)(wsb + 194695456);

    // ---- CSR build ----
    hipMemsetAsync(counts, 0, sizeof(int) * (N_NODES + 1), stream);
    hipLaunchKernelGGL(hist_kernel, dim3((E_TOT + 255) / 256), dim3(256), 0, stream, ei, counts);
    hipLaunchKernelGGL(scan_sums,   dim3(N_CHUNKS), dim3(256), 0, stream, counts, chunk_sums);
    hipLaunchKernelGGL(scan_chunks, dim3(1), dim3(64), 0, stream, chunk_sums, chunk_base);
    hipLaunchKernelGGL(scan_write,  dim3(N_CHUNKS), dim3(256), 0, stream,
                       counts, chunk_base, offsets, cursor);
    hipLaunchKernelGGL(scatter_kernel, dim3((E_TOT + 255) / 256), dim3(256), 0, stream,
                       ei, cursor, srcs);

    // ---- GAT weight repack (merged) ----
    hipLaunchKernelGGL(repack_gat_kernel, dim3(960), dim3(256), 0, stream,
                       Wl2, Wr2, Wl3, Wr3, BpL2, BpR2, BpL3, BpR3);

    // ---- layer 1 ----
    hipLaunchKernelGGL(l1_transform, dim3((N_NODES + 63) / 64), dim3(192), 0, stream,
                       x, Wl1, bl1, Wr1, br1, XLu, XRu, N_NODES);
    hipLaunchKernelGGL((gat_fused<64>), AGG_GRID, dim3(256), 0, stream,
                       XLu, XRu, att1, b1, offsets, srcs, h1u, N_NODES);
    // ---- layer 2 ----
    hipLaunchKernelGGL((mfma_gemmF<64, 384>), dim3(6, 391), dim3(256), 0, stream,
                       h1u, BpL2, BpR2, bl2, br2, XLb, XRb, N_NODES);
    hipLaunchKernelGGL((gat_fused<128>), AGG_GRID, dim3(256), 0, stream,
                       XLu, XRu, att2, b2, offsets, srcs, h2u, N_NODES);
    // ---- layer 3 ----
    hipLaunchKernelGGL((mfma_gemmF<128, 768>), dim3(12, 391), dim3(256), 0, stream,
                       h2u, BpL3, BpR3, bl3, br3, XLb, XRb, N_NODES);
    hipLaunchKernelGGL((gat_fused<256>), AGG_GRID, dim3(256), 0, stream,
                       XLu, XRu, att3, b3, offsets, srcs, h3u, N_NODES);

    // ---- decoder split-weight repack (merged; XR dead now) ----
    hipLaunchKernelGGL(repack_split3, dim3(3136), dim3(256), 0, stream,
                       Wd1, Wd2, Wd3, BhD1, BlD1, BhD2, BlD2, BhD3, BlD3);

    // ---- pool ----
    hipLaunchKernelGGL(pool_kernel, dim3(NUM_GRAPHS), dim3(256), 0, stream, h3u, batch, G);

    // ---- VAE heads + decoder ----
    hipLaunchKernelGGL((gemm_dec<false>), dim3(1, 64), dim3(256), 0, stream,
                       G, Wmu, bmu, out + MU_OFF, NUM_GRAPHS, 64, 256, 256, 64, 64);
    hipLaunchKernelGGL((gemm_dec<false>), dim3(1, 64), dim3(256), 0, stream,
                       G, Wlv, blv, out + LV_OFF, NUM_GRAPHS, 64, 256, 256, 64, 64);
    hipLaunchKernelGGL((mfma_dec<true>), dim3(2, 16), dim3(256), 0, stream,
                       out + MU_OFF, BhD1, BlD1, bd1, O1, NUM_GRAPHS, 256, 64, 256, 64, 256);
    hipLaunchKernelGGL((mfma_dec<true>), dim3(4, 16), dim3(256), 0, stream,
                       O1, BhD2, BlD2, bd2, O2, NUM_GRAPHS, 512, 256, 512, 256, 512);
    hipLaunchKernelGGL((mfma_dec<false>), dim3(10, 16), dim3(256), 0, stream,
                       O2, BhD3, BlD3, bd3, O3, NUM_GRAPHS, 1160, 512, 1280, 512, 1160);
    hipLaunchKernelGGL(assemble_kernel, dim3(NUM_GRAPHS), dim3(256), 0, stream, O3, out);
}